// Round 5
// baseline (176.432 us; speedup 1.0000x reference)
//
#include <hip/hip_runtime.h>
#include <stdint.h>

// Problem: cosine-similarity relations.
//   support: (2,5,1024,128) fp32 -> 10240 rows; query: (2,4,1024,128) -> 8192 rows
//   out: (2,4,5,1024,1024) fp32 = 167.8 MB
// Budget: dur ~= harness fill(103) + norm(3) + gemm. R5-R8 gemm ~= 68 us vs
// ~26 us write floor. DEAD THEORIES: NT stores (R7, -13 us regress: partial-
// line NT defeats L2 write-combine), XCD read-locality (R8, neutral), no-LDS
// per-tile fragment gather (R6, -26 us: vmem issue-bound).
// R9 theory: the one-shot block lifecycle (stage 64KB -> barrier -> compute ->
// store burst, NO loop) has nothing to pipeline; 64 KB LDS caps at 2 blocks/CU
// so each CU serializes 10 blocks ~5 rounds deep with phase latencies exposed.
// Fix: persistent-tile blocks. Each block: fixed (bi,tm) A-panel in VGPRs
// (one-time gather, amortized over 10 tiles), loop over 10 output tiles of
// 128x64 (j outer, tn inner), B panels (64x128 = 16 KB) double-buffered in
// LDS via the verified reg-stage + XOR-swizzle path. Per iter: barrier ->
// ds_write B(t+1) -> issue loads B(t+2) -> MFMA(B(t)) -> stores. Store bursts
// drain under the next iteration's staging/compute -> store-BW-bound steady
// state. LDS 32 KB, grid 512 = 2 blocks/CU, bi = blockIdx&7 keeps per-XCD
// hot read set ~0.5 MB.

#define S_ROWS 10240
#define Q_ROWS 8192

typedef __attribute__((ext_vector_type(8))) short short8;   // 8 bf16 (4 VGPRs)
typedef __attribute__((ext_vector_type(4))) float floatx4;  // 16x16 MFMA acc
typedef __attribute__((ext_vector_type(4))) unsigned int uint4x;  // 16 B chunk

__device__ static inline unsigned short f32_to_bf16_rne(float f) {
    union { float f; uint32_t u; } c; c.f = f;
    uint32_t u = c.u;
    uint32_t r = u + 0x7FFFu + ((u >> 16) & 1u);   // round-to-nearest-even
    return (unsigned short)(r >> 16);
}

// ---------------- Kernel 1: L2-normalize rows of 128, cast to bf16 ----------
__global__ __launch_bounds__(256) void norm_cast_kernel(
    const float* __restrict__ support, const float* __restrict__ query,
    unsigned short* __restrict__ sn, unsigned short* __restrict__ qn)
{
    int wave = blockIdx.x * 4 + (threadIdx.x >> 6);
    int lane = threadIdx.x & 63;

    const float* src;
    unsigned short* dst;
    if (wave < S_ROWS) {
        src = support + (size_t)wave * 128;
        dst = sn + (size_t)wave * 128;
    } else {
        int r = wave - S_ROWS;
        src = query + (size_t)r * 128;
        dst = qn + (size_t)r * 128;
    }

    float2 v = ((const float2*)src)[lane];
    float s = v.x * v.x + v.y * v.y;
    #pragma unroll
    for (int off = 32; off > 0; off >>= 1) s += __shfl_xor(s, off, 64);
    float inv = 1.0f / fmaxf(sqrtf(s), 1e-12f);

    unsigned short lo = f32_to_bf16_rne(v.x * inv);
    unsigned short hi = f32_to_bf16_rne(v.y * inv);
    ((uint32_t*)dst)[lane] = ((uint32_t)hi << 16) | (uint32_t)lo;
}

// ---------------- Kernel 2: persistent-tile batched C = Qn * Sn^T -----------
// 512 blocks x 256 threads (4 waves). Block owns (bi, tm, q): A-panel
// (128x128) in VGPRs; loops t=0..9 over tiles (j = t/2, tn = 2q + t&1) of
// 128 rows x 64 cols. B panels double-buffered in 2 x 16 KB swizzled LDS.
__global__ __launch_bounds__(256, 2) void gemm_bt_kernel(
    const unsigned short* __restrict__ qn, const unsigned short* __restrict__ sn,
    float* __restrict__ out)
{
    __shared__ unsigned short Bs[2][64 * 128];  // 2 x 16 KB, swizzled 16B units

    const int tid  = threadIdx.x;
    const int wave = tid >> 6;
    const int lane = tid & 63;

    const int x  = blockIdx.x;        // 0..511
    const int bi = x & 7;             // (b,i) = XCD id (round-robin dispatch)
    const int tm = (x >> 3) & 7;      // A-panel row block
    const int q  = x >> 6;            // 0..7 -> tn pair {2q, 2q+1}
    const int b  = bi >> 2;

    const int wm   = (wave >> 1) * 64;   // wave m-offset within 128
    const int wn   = (wave & 1) * 32;    // wave n-offset within 64
    const int ml   = lane & 15;
    const int quad = lane >> 4;

    // ---- A fragments: one-time per-lane gather from global (amortized 10x).
    // a[kb][mi] = Qn[row = tm*128 + wm + mi*16 + ml][k = kb*32 + quad*8 ..+8]
    const unsigned short* gA = qn + ((size_t)bi * 1024 + tm * 128) * 128;
    short8 a[4][4];
    #pragma unroll
    for (int kb = 0; kb < 4; ++kb)
        #pragma unroll
        for (int mi = 0; mi < 4; ++mi)
            a[kb][mi] = *(const short8*)&gA[
                (size_t)(wm + mi * 16 + ml) * 128 + (kb * 4 + quad) * 8];

    // ---- B panel pointers: tile t -> (j = t>>1, tn = q*2 + (t&1)) ----
    const unsigned short* sb = sn + (size_t)b * 5 * 1024 * 128;
    const uint4x* bp[10];
    #pragma unroll
    for (int t = 0; t < 10; ++t) {
        const int j  = t >> 1;
        const int tn = q * 2 + (t & 1);
        bp[t] = (const uint4x*)(sb + ((size_t)j * 1024 + tn * 64) * 128);
    }

    // Reg-staging: 16 KB panel = 1024 16B-units; thread t stages 4 units.
    // ds_write address XOR-swizzled (verified R5 path); loads linear/coalesced.
    uint4x rb[2][4];
    #pragma unroll
    for (int it = 0; it < 4; ++it) rb[0][it] = bp[0][it * 256 + tid];
    #pragma unroll
    for (int it = 0; it < 4; ++it) rb[1][it] = bp[1][it * 256 + tid];

    #pragma unroll
    for (int it = 0; it < 4; ++it) {           // prologue: B(0) -> Bs[0]
        const int u  = it * 256 + tid;
        const int r  = u >> 4;
        const int cl = u & 15;
        const int su = (r << 4) | (cl ^ (r & 15));
        *(uint4x*)&Bs[0][su * 8] = rb[0][it];
    }

    float* gC0 = out + ((size_t)(bi * 5) << 20) + (size_t)(tm * 128) * 1024;

    #pragma unroll
    for (int t = 0; t < 10; ++t) {
        __syncthreads();   // B(t) staged; all waves done reading Bs[(t+1)&1]

        if (t < 9) {       // stage B(t+1) -> Bs[(t+1)&1] (regs loaded earlier)
            #pragma unroll
            for (int it = 0; it < 4; ++it) {
                const int u  = it * 256 + tid;
                const int r  = u >> 4;
                const int cl = u & 15;
                const int su = (r << 4) | (cl ^ (r & 15));
                *(uint4x*)&Bs[(t + 1) & 1][su * 8] = rb[(t + 1) & 1][it];
            }
        }
        if (t < 8) {       // issue loads for B(t+2) into the freed reg set
            #pragma unroll
            for (int it = 0; it < 4; ++it)
                rb[t & 1][it] = bp[t + 2][it * 256 + tid];
        }

        // ---- compute tile t from Bs[t&1] ----
        floatx4 acc[4][2] = {};
        #pragma unroll
        for (int kb = 0; kb < 4; ++kb) {
            const int c = kb * 4 + quad;
            short8 bf[2];
            #pragma unroll
            for (int ni = 0; ni < 2; ++ni) {
                const int brow = wn + ni * 16 + ml;   // brow & 15 == ml
                bf[ni] = *(const short8*)&Bs[t & 1][((brow << 4) | (c ^ ml)) * 8];
            }
            #pragma unroll
            for (int mi = 0; mi < 4; ++mi)
                #pragma unroll
                for (int ni = 0; ni < 2; ++ni)
                    acc[mi][ni] = __builtin_amdgcn_mfma_f32_16x16x32_bf16(
                        a[kb][mi], bf[ni], acc[mi][ni], 0, 0, 0);
        }

        // ---- epilogue tile t (C/D layout col=lane&15, row=quad*4+reg) ----
        const int j  = t >> 1;
        const int tn = q * 2 + (t & 1);
        float* gC = gC0 + ((size_t)j << 20) + tn * 64;
        #pragma unroll
        for (int mi = 0; mi < 4; ++mi) {
            #pragma unroll
            for (int r = 0; r < 4; ++r) {
                const int row = wm + mi * 16 + quad * 4 + r;
                float* rowp = gC + (size_t)row * 1024 + wn + ml;
                #pragma unroll
                for (int ni = 0; ni < 2; ++ni)
                    rowp[ni * 16] = acc[mi][ni][r];
            }
        }
    }
}

extern "C" void kernel_launch(void* const* d_in, const int* in_sizes, int n_in,
                              void* d_out, int out_size, void* d_ws, size_t ws_size,
                              hipStream_t stream) {
    const float* support = (const float*)d_in[0];   // (2,5,1024,128)
    const float* query   = (const float*)d_in[1];   // (2,4,1024,128)
    unsigned short* sn = (unsigned short*)d_ws;             // 10240*128 bf16
    unsigned short* qn = sn + (size_t)S_ROWS * 128;         //  8192*128 bf16
    float* out = (float*)d_out;

    norm_cast_kernel<<<dim3((S_ROWS + Q_ROWS) / 4), dim3(256), 0, stream>>>(
        support, query, sn, qn);
    gemm_bt_kernel<<<dim3(512), dim3(256), 0, stream>>>(qn, sn, out);
}

// Round 7
// 175.297 us; speedup vs baseline: 1.0065x; 1.0065x over previous
//
#include <hip/hip_runtime.h>
#include <stdint.h>

// Problem: cosine-similarity relations.
//   support: (2,5,1024,128) fp32 -> 10240 rows; query: (2,4,1024,128) -> 8192 rows
//   out: (2,4,5,1024,1024) fp32 = 167.8 MB
// Budget: dur ~= harness fill(100, in-window) + norm(3) + gemm(~68) vs ~26 us
// write floor. DEAD THEORIES: NT stores (R7 -13), no-LDS reads (R6 -26),
// XCD read-locality (R8 neutral), persistent pipelined blocks (R9 neutral).
// R10 theory: the 174-plateau invariant across R5/R8/R9 is the EPILOGUE:
// per-lane scalar dword stores -> each wave-inst writes 4 discontiguous 64B
// segments (quads on rows 4KB apart). Fill kernel: 6.7 TB/s with contiguous
// 1KB wave-insts; our gemm: 167.8MB/68us = 2.5 TB/s effective. Store-
// coalescing-bound. Fix (single variable vs R8): after compute, transpose
// each wave's 64x64 acc tile via per-wave-private LDS scratch (reuse dead
// As/Bs, stride 68 floats -> 2-way bank alias = free, m136), then
// global_store_dwordx4: wave-inst = 4 rows x 256B contiguous (full lines),
// 16 store insts/lane instead of 64.
// (R6 submission lost to GPUAcquisitionTimeout; identical resubmit.)

#define S_ROWS 10240
#define Q_ROWS 8192

typedef __attribute__((ext_vector_type(8))) short short8;   // 8 bf16 (4 VGPRs)
typedef __attribute__((ext_vector_type(4))) float floatx4;  // 16x16 MFMA acc
typedef __attribute__((ext_vector_type(4))) unsigned int uint4x;  // 16 B chunk

__device__ static inline unsigned short f32_to_bf16_rne(float f) {
    union { float f; uint32_t u; } c; c.f = f;
    uint32_t u = c.u;
    uint32_t r = u + 0x7FFFu + ((u >> 16) & 1u);   // round-to-nearest-even
    return (unsigned short)(r >> 16);
}

// ---------------- Kernel 1: L2-normalize rows of 128, cast to bf16 ----------
__global__ __launch_bounds__(256) void norm_cast_kernel(
    const float* __restrict__ support, const float* __restrict__ query,
    unsigned short* __restrict__ sn, unsigned short* __restrict__ qn)
{
    int wave = blockIdx.x * 4 + (threadIdx.x >> 6);
    int lane = threadIdx.x & 63;

    const float* src;
    unsigned short* dst;
    if (wave < S_ROWS) {
        src = support + (size_t)wave * 128;
        dst = sn + (size_t)wave * 128;
    } else {
        int r = wave - S_ROWS;
        src = query + (size_t)r * 128;
        dst = qn + (size_t)r * 128;
    }

    float2 v = ((const float2*)src)[lane];
    float s = v.x * v.x + v.y * v.y;
    #pragma unroll
    for (int off = 32; off > 0; off >>= 1) s += __shfl_xor(s, off, 64);
    float inv = 1.0f / fmaxf(sqrtf(s), 1e-12f);

    unsigned short lo = f32_to_bf16_rne(v.x * inv);
    unsigned short hi = f32_to_bf16_rne(v.y * inv);
    ((uint32_t*)dst)[lane] = ((uint32_t)hi << 16) | (uint32_t)lo;
}

// ---------------- Kernel 2: batched C = Qn * Sn^T via bf16 MFMA -------------
// 256 threads (4 waves), 128x128 tile, 64x64 per wave. A/B tiles staged in
// LDS (64 KB) with XOR-swizzled 16B units; conflict-free ds_read_b128.
// R10: epilogue transposes acc through LDS scratch -> dwordx4 stores.
__global__ __launch_bounds__(256) void gemm_bt_kernel(
    const unsigned short* __restrict__ qn, const unsigned short* __restrict__ sn,
    float* __restrict__ out)
{
    __shared__ unsigned short smem[2 * 128 * 128];   // 64 KB
    unsigned short* As = smem;                       // 32 KB, swizzled 16B units
    unsigned short* Bs = smem + 128 * 128;           // 32 KB, swizzled 16B units

    const int tid  = threadIdx.x;
    const int wave = tid >> 6;
    const int lane = tid & 63;

    // Tile decode: bid -> xcd-chunked (T1, bijective: 2560 % 8 == 0).
    const int bid = blockIdx.x;
    const int bi  = bid & 7;          // (b,i) = XCD id: per-XCD A set = 1 MB
    const int pos = bid >> 3;         // 0..319 within this XCD's chunk
    const int j   = pos >> 6;         // 0..4
    const int r6  = pos & 63;
    const int tm  = r6 >> 3;          // tn fastest -> A-panel reuse burst
    const int tn  = r6 & 7;
    const int b   = bi >> 2;

    const unsigned short* gA = qn + (((size_t)bi * 1024 + tm * 128) * 128);
    const unsigned short* gB = sn + (((size_t)(b * 5 + j) * 1024 + tn * 128) * 128);

    // Stage 2 x 32 KB. Tile = 2048 16B-units; thread t does units t+256*it.
    // Global loads fully coalesced; ds_write address swizzled.
    uint4x ra[8], rb[8];
    #pragma unroll
    for (int it = 0; it < 8; ++it) {
        ra[it] = ((const uint4x*)gA)[it * 256 + tid];
        rb[it] = ((const uint4x*)gB)[it * 256 + tid];
    }
    #pragma unroll
    for (int it = 0; it < 8; ++it) {
        const int u  = it * 256 + tid;
        const int r  = u >> 4;
        const int cl = u & 15;
        const int su = (r << 4) | (cl ^ (r & 15));   // swizzled LDS unit
        *(uint4x*)&As[su * 8] = ra[it];
        *(uint4x*)&Bs[su * 8] = rb[it];
    }

    const int wm   = (wave >> 1) * 64;
    const int wn   = (wave & 1) * 64;
    const int ml   = lane & 15;
    const int quad = lane >> 4;

    floatx4 acc[4][4] = {};

    __syncthreads();

    #pragma unroll
    for (int kb = 0; kb < 4; ++kb) {
        const int c = kb * 4 + quad;     // 16B-unit column (k-chunk) index
        short8 a[4], bf[4];
        #pragma unroll
        for (int mi = 0; mi < 4; ++mi) {
            const int arow = wm + mi * 16 + ml;          // arow & 15 == ml
            a[mi] = *(const short8*)&As[(((arow << 4) | (c ^ ml))) * 8];
        }
        #pragma unroll
        for (int ni = 0; ni < 4; ++ni) {
            const int brow = wn + ni * 16 + ml;
            bf[ni] = *(const short8*)&Bs[(((brow << 4) | (c ^ ml))) * 8];
        }
        #pragma unroll
        for (int mi = 0; mi < 4; ++mi)
            #pragma unroll
            for (int ni = 0; ni < 4; ++ni)
                acc[mi][ni] = __builtin_amdgcn_mfma_f32_16x16x32_bf16(
                    a[mi], bf[ni], acc[mi][ni], 0, 0, 0);
    }

    // ---- R10 epilogue: per-wave LDS transpose -> float4 row stores ----
    // acc layout (m89/m91): value (mi,ni,r) sits at row wm+mi*16+quad*4+r,
    // col wn+ni*16+ml. Two passes of 32 rows x 64 cols through scratch
    // (stride 68 floats: quads land 16 banks apart -> 2-way alias, free).
    float* scratch = (float*)smem;             // reuse; 4 waves * 8704 B
    const int wbase = wave * (32 * 68);
    float* gC = out + ((size_t)(bi * 5 + j) << 20)
                    + (size_t)(tm * 128) * 1024 + tn * 128;

    __syncthreads();   // everyone done reading As/Bs before scratch overwrite

    #pragma unroll
    for (int p = 0; p < 2; ++p) {
        #pragma unroll
        for (int mi2 = 0; mi2 < 2; ++mi2) {
            const int mi = p * 2 + mi2;
            #pragma unroll
            for (int ni = 0; ni < 4; ++ni)
                #pragma unroll
                for (int r = 0; r < 4; ++r)
                    scratch[wbase + (mi2 * 16 + quad * 4 + r) * 68 + ni * 16 + ml]
                        = acc[mi][ni][r];
        }
        __syncthreads();   // orders write->read (uniform control flow)

        // Read back row-major: iter covers 4 rows x 64 cols; per wave-inst
        // the global store is 4 segments of 256 B (two full 128B lines each).
        #pragma unroll
        for (int it = 0; it < 8; ++it) {
            const int lr = it * 4 + quad;          // local row 0..31
            floatx4 v = *(const floatx4*)&scratch[wbase + lr * 68 + ml * 4];
            float* dst = gC + (size_t)(wm + p * 32 + lr) * 1024 + wn + ml * 4;
            *(floatx4*)dst = v;
        }
        __syncthreads();   // pass-0 reads drained before pass-1 overwrites
    }
}

extern "C" void kernel_launch(void* const* d_in, const int* in_sizes, int n_in,
                              void* d_out, int out_size, void* d_ws, size_t ws_size,
                              hipStream_t stream) {
    const float* support = (const float*)d_in[0];   // (2,5,1024,128)
    const float* query   = (const float*)d_in[1];   // (2,4,1024,128)
    unsigned short* sn = (unsigned short*)d_ws;             // 10240*128 bf16
    unsigned short* qn = sn + (size_t)S_ROWS * 128;         //  8192*128 bf16
    float* out = (float*)d_out;

    norm_cast_kernel<<<dim3((S_ROWS + Q_ROWS) / 4), dim3(256), 0, stream>>>(
        support, query, sn, qn);
    gemm_bt_kernel<<<dim3(2560), dim3(256), 0, stream>>>(qn, sn, out);
}

// Round 12
// 172.840 us; speedup vs baseline: 1.0208x; 1.0142x over previous
//
#include <hip/hip_runtime.h>
#include <stdint.h>

// Problem: cosine-similarity relations.
//   support: (2,5,1024,128) fp32 -> 10240 rows; query: (2,4,1024,128) -> 8192 rows
//   out: (2,4,5,1024,1024) fp32 = 167.8 MB
// BUDGET (recalibrated R11): harness fill writes 671 MB = 4x out -> timed
// window ~= fill_ws(103) + fill_out(26, below top-5 cutoff) + norm(3) +
// gemm(~42). Gemm is ~12-15 us above its ~28-30 us write+tail floor, which is
// why 5 structural variants (NT stores -13, no-LDS -26, XCD map 0, persistent
// pipeline 0, coalesced epilogue 0) all landed at 174-176: the gemm is near-
// floor and ~74% of dur_us is harness-fixed.
// R11 (last addressable term): all neutral variants ran at 2 blocks/CU (64 KB
// LDS). One-shot blocks end in a store burst + barrier whose vmcnt(0) drains
// are exposed at 2-deep residency. Shrink tile to 128x64 -> 48 KB LDS -> 3
// blocks/CU (12 waves/CU, +50% TLP): other blocks' compute covers each
// block's staging-wait and store-drain (m114 wave-level overlap). Reads grow
// to ~245 MB but are L2/L3-served (~10 us aggregate, non-binding).
// (R8-R11 submissions lost to GPUAcquisitionTimeout; identical resubmit.)

#define S_ROWS 10240
#define Q_ROWS 8192

typedef __attribute__((ext_vector_type(8))) short short8;   // 8 bf16 (4 VGPRs)
typedef __attribute__((ext_vector_type(4))) float floatx4;  // 16x16 MFMA acc
typedef __attribute__((ext_vector_type(4))) unsigned int uint4x;  // 16 B chunk

__device__ static inline unsigned short f32_to_bf16_rne(float f) {
    union { float f; uint32_t u; } c; c.f = f;
    uint32_t u = c.u;
    uint32_t r = u + 0x7FFFu + ((u >> 16) & 1u);   // round-to-nearest-even
    return (unsigned short)(r >> 16);
}

// ---------------- Kernel 1: L2-normalize rows of 128, cast to bf16 ----------
__global__ __launch_bounds__(256) void norm_cast_kernel(
    const float* __restrict__ support, const float* __restrict__ query,
    unsigned short* __restrict__ sn, unsigned short* __restrict__ qn)
{
    int wave = blockIdx.x * 4 + (threadIdx.x >> 6);
    int lane = threadIdx.x & 63;

    const float* src;
    unsigned short* dst;
    if (wave < S_ROWS) {
        src = support + (size_t)wave * 128;
        dst = sn + (size_t)wave * 128;
    } else {
        int r = wave - S_ROWS;
        src = query + (size_t)r * 128;
        dst = qn + (size_t)r * 128;
    }

    float2 v = ((const float2*)src)[lane];
    float s = v.x * v.x + v.y * v.y;
    #pragma unroll
    for (int off = 32; off > 0; off >>= 1) s += __shfl_xor(s, off, 64);
    float inv = 1.0f / fmaxf(sqrtf(s), 1e-12f);

    unsigned short lo = f32_to_bf16_rne(v.x * inv);
    unsigned short hi = f32_to_bf16_rne(v.y * inv);
    ((uint32_t*)dst)[lane] = ((uint32_t)hi << 16) | (uint32_t)lo;
}

// ---------------- Kernel 2: batched C = Qn * Sn^T via bf16 MFMA -------------
// 256 threads (4 waves), 128x64 tile, 64x32 per wave. A (128x128, 32 KB) and
// B (64x128, 16 KB) staged in LDS with XOR-swizzled 16B units; conflict-free
// ds_read_b128. 48 KB LDS -> 3 blocks/CU.
__global__ __launch_bounds__(256, 3) void gemm_bt_kernel(
    const unsigned short* __restrict__ qn, const unsigned short* __restrict__ sn,
    float* __restrict__ out)
{
    __shared__ unsigned short As[128 * 128];  // 32 KB, swizzled 16B units
    __shared__ unsigned short Bs[64 * 128];   // 16 KB, swizzled 16B units

    const int tid  = threadIdx.x;
    const int wave = tid >> 6;
    const int lane = tid & 63;

    // Tile decode: bid -> xcd-chunked (bijective: 5120 % 8 == 0).
    const int bid = blockIdx.x;
    const int bi  = bid & 7;          // (b,i) = XCD id
    const int pos = bid >> 3;         // 0..639 within this XCD's chunk
    const int j   = pos >> 7;         // 0..4
    const int rr  = pos & 127;
    const int tm  = rr >> 4;          // 0..7  (M block of 128)
    const int tn  = rr & 15;          // 0..15 (N block of 64), fastest
    const int b   = bi >> 2;

    const unsigned short* gA = qn + (((size_t)bi * 1024 + tm * 128) * 128);
    const unsigned short* gB = sn + (((size_t)(b * 5 + j) * 1024 + tn * 64) * 128);

    // Stage A: 2048 16B-units (8/thread); B: 1024 units (4/thread).
    // Global loads fully coalesced; ds_write address swizzled (row=16 units).
    uint4x ra[8], rb[4];
    #pragma unroll
    for (int it = 0; it < 8; ++it) ra[it] = ((const uint4x*)gA)[it * 256 + tid];
    #pragma unroll
    for (int it = 0; it < 4; ++it) rb[it] = ((const uint4x*)gB)[it * 256 + tid];

    #pragma unroll
    for (int it = 0; it < 8; ++it) {
        const int u  = it * 256 + tid;
        const int r  = u >> 4;
        const int cl = u & 15;
        const int su = (r << 4) | (cl ^ (r & 15));   // swizzled LDS unit
        *(uint4x*)&As[su * 8] = ra[it];
    }
    #pragma unroll
    for (int it = 0; it < 4; ++it) {
        const int u  = it * 256 + tid;
        const int r  = u >> 4;
        const int cl = u & 15;
        const int su = (r << 4) | (cl ^ (r & 15));
        *(uint4x*)&Bs[su * 8] = rb[it];
    }

    const int wm   = (wave >> 1) * 64;   // 0 / 64
    const int wn   = (wave & 1) * 32;    // 0 / 32
    const int ml   = lane & 15;
    const int quad = lane >> 4;

    floatx4 acc[4][2] = {};

    __syncthreads();

    #pragma unroll
    for (int kb = 0; kb < 4; ++kb) {
        const int c = kb * 4 + quad;     // 16B-unit column (k-chunk) index
        short8 a[4], bf[2];
        #pragma unroll
        for (int mi = 0; mi < 4; ++mi) {
            const int arow = wm + mi * 16 + ml;          // arow & 15 == ml
            a[mi] = *(const short8*)&As[(((arow << 4) | (c ^ ml))) * 8];
        }
        #pragma unroll
        for (int ni = 0; ni < 2; ++ni) {
            const int brow = wn + ni * 16 + ml;          // brow & 15 == ml
            bf[ni] = *(const short8*)&Bs[(((brow << 4) | (c ^ ml))) * 8];
        }
        #pragma unroll
        for (int mi = 0; mi < 4; ++mi)
            #pragma unroll
            for (int ni = 0; ni < 2; ++ni)
                acc[mi][ni] = __builtin_amdgcn_mfma_f32_16x16x32_bf16(
                    a[mi], bf[ni], acc[mi][ni], 0, 0, 0);
    }

    // Epilogue: C/D layout col=lane&15, row=quad*4+reg (m89/m91-verified).
    // Plain scalar stores (R10 proved instruction-level pattern is neutral).
    float* gC = out + ((size_t)(bi * 5 + j) << 20)
                    + (size_t)(tm * 128) * 1024 + tn * 64;
    #pragma unroll
    for (int mi = 0; mi < 4; ++mi) {
        #pragma unroll
        for (int r = 0; r < 4; ++r) {
            const int row = wm + mi * 16 + quad * 4 + r;
            float* rowp = gC + (size_t)row * 1024 + wn + ml;
            #pragma unroll
            for (int ni = 0; ni < 2; ++ni)
                rowp[ni * 16] = acc[mi][ni][r];
        }
    }
}

extern "C" void kernel_launch(void* const* d_in, const int* in_sizes, int n_in,
                              void* d_out, int out_size, void* d_ws, size_t ws_size,
                              hipStream_t stream) {
    const float* support = (const float*)d_in[0];   // (2,5,1024,128)
    const float* query   = (const float*)d_in[1];   // (2,4,1024,128)
    unsigned short* sn = (unsigned short*)d_ws;             // 10240*128 bf16
    unsigned short* qn = sn + (size_t)S_ROWS * 128;         //  8192*128 bf16
    float* out = (float*)d_out;

    norm_cast_kernel<<<dim3((S_ROWS + Q_ROWS) / 4), dim3(256), 0, stream>>>(
        support, query, sn, qn);
    gemm_bt_kernel<<<dim3(5120), dim3(256), 0, stream>>>(qn, sn, out);
}